// Round 12
// baseline (333.233 us; speedup 1.0000x reference)
//
#include <hip/hip_runtime.h>

// ---------------------------------------------------------------------------
// GraphConv x3 + FC on MI355X — R18: degree-sorted agg (divergence fix).
// Identity: (A x0)K1 + (A^2 x0)K2 + (A^3 x0)K3 = A(u1 + A(u2 + A u3)),
// u_m = x0 K_m (N x 64). 64-dim propagation (128B gather rows).
// R18: agg64 waves own 8 nodes, wave time = max(deg of 8) ~ 1.6x mean
// (Poisson 16). partB now emits a within-bucket degree-sorted permutation
// (LDS counting sort, no extra kernels); agg processes perm order so the
// 8 nodes per wave have ~equal degree -> inflation ~1.05x. gemm_u frozen
// (R16 structure: LDS B-panel, 4x4 tiles, prefetch, XCD sibling swizzle).
// ---------------------------------------------------------------------------

typedef short bf16x8 __attribute__((ext_vector_type(8)));
typedef float f32x4 __attribute__((ext_vector_type(4)));

#define CAPB 8192   // bucket capacity (mean 4082, sigma ~64 -> 64 sigma slack)

__device__ inline float bf2f(unsigned short u) {
    union { unsigned int i; float f; } v; v.i = ((unsigned int)u) << 16; return v.f;
}
__device__ inline unsigned short f2bf(float f) {
    union { float f; unsigned int i; } v; v.f = f;
    unsigned int r = v.i + 0x7FFFu + ((v.i >> 16) & 1u);   // RNE
    return (unsigned short)(r >> 16);
}

// ---- prep: stage1 mats [0,64) | edge partition [64,64+NA) ------------------
__global__ __launch_bounds__(512) void prep_kernel(
    const float* __restrict__ Wr2, const float* __restrict__ Wo2,
    const float* __restrict__ fcw, float* __restrict__ K0_2, float* __restrict__ K1_2,
    const int* __restrict__ src, const int* __restrict__ dst,
    int* __restrict__ gcur, unsigned int* __restrict__ bucketed, int e, int NA, int NB) {
    int b = blockIdx.x, t = threadIdx.x;
    if (b < 64) {
        if (t < 256) {
            int matid = b >> 5;
            const float* W = matid ? Wr2 : Wo2;
            float* K = matid ? K1_2 : K0_2;
            int i = t & 127;
            int j = (b & 31) * 2 + (t >> 7);
            float acc = 0.f;
            for (int k = 0; k < 128; k++) acc += W[k * 128 + i] * fcw[j * 128 + k];
            K[i * 64 + j] = acc;
        }
        return;
    }
    b -= 64;
    if (b < NA) {
        __shared__ int sHist[512], sScan[512], sExcl[512], sGbase[512];
        __shared__ unsigned int lbuf[2048];
        __shared__ unsigned short lbkt[2048];
        int e0 = b * 2048;
        int cnt = e - e0; if (cnt > 2048) cnt = 2048;
        sHist[t] = 0;
        __syncthreads();
        unsigned int pk[4]; int bk[4];
#pragma unroll
        for (int k = 0; k < 4; k++) {
            int j = t + k * 512;
            if (j < cnt) {
                int d = dst[e0 + j], s = src[e0 + j];
                bk[k] = d >> 8;
                pk[k] = ((unsigned int)s << 8) | (unsigned int)(d & 255);
                atomicAdd(&sHist[bk[k]], 1);
            } else bk[k] = -1;
        }
        __syncthreads();
        int h = sHist[t];
        if (t < NB && h > 0) sGbase[t] = atomicAdd(&gcur[t], h);
        else sGbase[t] = 0;
        int xv = h; sScan[t] = xv; __syncthreads();
        for (int o = 1; o < 512; o <<= 1) {
            int y = (t >= o) ? sScan[t - o] : 0;
            __syncthreads();
            xv += y; sScan[t] = xv;
            __syncthreads();
        }
        sExcl[t] = xv - h;      // block-local exclusive offsets per bucket
        sHist[t] = 0;           // becomes local cursor
        __syncthreads();
#pragma unroll
        for (int k = 0; k < 4; k++) {
            if (bk[k] >= 0) {
                int r = atomicAdd(&sHist[bk[k]], 1);
                int pos = sExcl[bk[k]] + r;
                lbuf[pos] = pk[k];
                lbkt[pos] = (unsigned short)bk[k];
            }
        }
        __syncthreads();
        for (int j = t; j < cnt; j += 512) {
            int b2 = lbkt[j];
            int idx = sGbase[b2] + (j - sExcl[b2]);
            if (idx < CAPB) bucketed[(size_t)b2 * CAPB + idx] = lbuf[j];
        }
    }
}

// ---- pass B: per-bucket deg/start/csr + within-bucket degree sort ----------
__global__ __launch_bounds__(256) void partB_kernel(
    const unsigned int* __restrict__ bucketed, const int* __restrict__ gcur,
    int* __restrict__ deg, int* __restrict__ start, int* __restrict__ csr,
    int* __restrict__ perm, int n) {
    int b = blockIdx.x, t = threadIdx.x;
    __shared__ int ldeg[256], lscan[256], red[256];
    __shared__ int sh2[128], se2[128], sc2[128];
    __shared__ int csr_base_s;
    int cnt = gcur[b]; if (cnt > CAPB) cnt = CAPB;
    // csr base = sum of counts of buckets < b
    int part = 0;
    for (int q = t; q < b; q += 256) { int c = gcur[q]; part += (c > CAPB ? CAPB : c); }
    red[t] = part; __syncthreads();
    for (int o = 128; o > 0; o >>= 1) { if (t < o) red[t] += red[t + o]; __syncthreads(); }
    if (t == 0) csr_base_s = red[0];
    ldeg[t] = 0;
    __syncthreads();
    const unsigned int* bd = bucketed + (size_t)b * CAPB;
    for (int j = t; j < cnt; j += 256) atomicAdd(&ldeg[bd[j] & 255], 1);
    __syncthreads();
    int h = ldeg[t];
    int xv = h; lscan[t] = xv; __syncthreads();
    for (int o = 1; o < 256; o <<= 1) {
        int y = (t >= o) ? lscan[t - o] : 0;
        __syncthreads();
        xv += y; lscan[t] = xv;
        __syncthreads();
    }
    int excl = xv - h;
    int csr_base = csr_base_s;
    int node = b * 256 + t;
    if (node < n) { deg[node] = h; start[node] = csr_base + excl; }
    __syncthreads();
    lscan[t] = excl;    // per-local-node exclusive offset
    ldeg[t] = 0;        // cursor
    __syncthreads();
    for (int j = t; j < cnt; j += 256) {
        unsigned int pkd = bd[j];
        int d = pkd & 255;
        int r = atomicAdd(&ldeg[d], 1);
        csr[csr_base + lscan[d] + r] = (int)(pkd >> 8);
    }

    // ---- within-bucket degree counting sort -> perm ------------------------
    // positions [b*256, b*256+nv) get this bucket's valid nodes sorted by
    // deg (bin = min(h,127)); nv = min(256, n-b*256) so perm is a complete
    // permutation of [0,n).
    if (t < 128) { sh2[t] = 0; sc2[t] = 0; }
    __syncthreads();
    int bin = -1;
    if (node < n) { bin = h < 127 ? h : 127; atomicAdd(&sh2[bin], 1); }
    __syncthreads();
    int sval = (t < 128) ? sh2[t] : 0;
    if (t < 128) se2[t] = sval;
    __syncthreads();
    for (int o = 1; o < 128; o <<= 1) {
        int y = (t >= o && t < 128) ? se2[t - o] : 0;
        __syncthreads();
        if (t < 128) { sval += y; se2[t] = sval; }
        __syncthreads();
    }
    if (node < n) {
        int r = atomicAdd(&sc2[bin], 1);
        int pos = b * 256 + (se2[bin] - sh2[bin]) + r;   // exclusive scan + rank
        perm[pos] = node;
    }
}

// ---- stage2: K*_1 from layer-1 (0-based) weights ---------------------------
__global__ __launch_bounds__(256) void stage2_kernel(
    const float* __restrict__ Wr1, const float* __restrict__ Wo1,
    const float* __restrict__ K0_2, const float* __restrict__ K1_2,
    float* __restrict__ K0_1, float* __restrict__ K1_1, float* __restrict__ K2_1) {
    int b = blockIdx.x, t = threadIdx.x;
    int matid = b >> 5;
    int i = t & 127;
    int j = (b & 31) * 2 + (t >> 7);
    float acc = 0.f;
    if (matid == 0) {
        for (int k = 0; k < 128; k++) acc += Wo1[k * 128 + i] * K0_2[k * 64 + j];
        K0_1[i * 64 + j] = acc;
    } else if (matid == 1) {
        for (int k = 0; k < 128; k++)
            acc += Wr1[k * 128 + i] * K0_2[k * 64 + j] + Wo1[k * 128 + i] * K1_2[k * 64 + j];
        K1_1[i * 64 + j] = acc;
    } else {
        for (int k = 0; k < 128; k++) acc += Wr1[k * 128 + i] * K1_2[k * 64 + j];
        K2_1[i * 64 + j] = acc;
    }
}

// ---- stage3: final K0..K3 packed bf16 (permuted slots) + bias vectors ------
// Nw slot p = ((c&3)<<4)|(c>>2) holds logical output column c, so gemm_u's
// tile t / lane m (reading slot t*16+m) emits logical column 4m+t.
__global__ __launch_bounds__(256) void stage3_kernel(
    const float* __restrict__ Wr0, const float* __restrict__ Wo0,
    const float* __restrict__ K0_1, const float* __restrict__ K1_1, const float* __restrict__ K2_1,
    const float* __restrict__ K0_2, const float* __restrict__ K1_2,
    const float* __restrict__ br, const float* __restrict__ fcw, const float* __restrict__ fcb,
    unsigned short* __restrict__ Nw, float* __restrict__ Bv) {
    int b = blockIdx.x, t = threadIdx.x;
    if (b < 128) {
        int matid = b >> 5;
        int i = t & 127;
        int o = (b & 31) * 2 + (t >> 7);
        float acc = 0.f;
        if (matid == 0) {
            for (int k = 0; k < 128; k++) acc += Wo0[k * 128 + i] * K0_1[k * 64 + o];
        } else if (matid == 1) {
            for (int k = 0; k < 128; k++)
                acc += Wr0[k * 128 + i] * K0_1[k * 64 + o] + Wo0[k * 128 + i] * K1_1[k * 64 + o];
        } else if (matid == 2) {
            for (int k = 0; k < 128; k++)
                acc += Wr0[k * 128 + i] * K1_1[k * 64 + o] + Wo0[k * 128 + i] * K2_1[k * 64 + o];
        } else {
            for (int k = 0; k < 128; k++) acc += Wr0[k * 128 + i] * K2_1[k * 64 + o];
        }
        int p = ((o & 3) << 4) | (o >> 2);
        Nw[p * 512 + matid * 128 + i] = f2bf(acc);
        return;
    }
    const float* br0 = br;
    const float* br1 = br + 128;
    const float* br2 = br + 256;
    int j = t & 63;
    int which = t >> 6;
    if (which == 0) {
        float acc = fcb[j];
        for (int k = 0; k < 128; k++) acc += br2[k] * fcw[j * 128 + k];
        for (int k = 0; k < 128; k++) acc += br1[k] * K0_2[k * 64 + j];
        for (int k = 0; k < 128; k++) acc += br0[k] * K0_1[k * 64 + j];
        Bv[j] = acc;                       // B0
    } else if (which == 1) {
        float acc = 0.f;
        for (int k = 0; k < 128; k++) acc += br1[k] * K1_2[k * 64 + j];
        for (int k = 0; k < 128; k++) acc += br0[k] * K1_1[k * 64 + j];
        Bv[64 + j] = acc;                  // B1
    } else if (which == 2) {
        float acc = 0.f;
        for (int k = 0; k < 128; k++) acc += br0[k] * K2_1[k * 64 + j];
        Bv[128 + j] = acc;                 // B2
    }
}

// ---- gemm_u: U[m][n][64] = bf16(x0 @ K_m), m=0..3, MFMA ---------------------
// Sibling swizzle: xcd=bid&7, matid=(bid>>3)&3, blk=(bid>>5)*8+xcd so the 4
// blocks sharing x rows land on the same XCD. B-panel staged in LDS once.
// 4 waves x 4 tiles per block with 1-tile x prefetch (regs: a16+v32+acc16+bq16).
__global__ __launch_bounds__(256, 4) void gemm_u_kernel(
    const float* __restrict__ x, const unsigned short* __restrict__ Nw,
    unsigned short* __restrict__ U, int n, int NGB) {
    __shared__ unsigned short Blds[8192];   // 16 KB
    int bid   = blockIdx.x;
    int matid = (bid >> 3) & 3;
    int blk   = (bid >> 5) * 8 + (bid & 7);
    if (blk >= NGB) return;                 // uniform per block (before syncthreads)
    int tid   = threadIdx.x;

    // stage B[matid]: 1024 x 16B groups, contiguous LDS writes
    {
        const uint4* nw4 = (const uint4*)Nw;   // Nw: 64 slots x 512 elems = 64 x 64 uint4
        uint4* lds4 = (uint4*)Blds;
        for (int g = tid; g < 1024; g += 256) {
            int slot = g & 63;
            int kq   = g >> 6;                 // kk*4+quad
            lds4[g] = nw4[(size_t)slot * 64 + matid * 16 + kq];
        }
    }
    __syncthreads();

    int wave = tid >> 6;
    int lane = tid & 63;
    int m    = lane & 15;
    int quad = lane >> 4;
    size_t n64 = (size_t)n * 64;
    unsigned short* up = U + (size_t)matid * n64;

    const int t0 = blk * 16 + wave * 4;

    // prologue: load tile t0 (row-clamped)
    float4 v[8];
    {
        int arow = t0 * 16 + m; if (arow >= n) arow = n - 1;
        const float* xr = x + (size_t)arow * 128 + quad * 8;
#pragma unroll
        for (int kk = 0; kk < 4; kk++) {
            v[2 * kk]     = *(const float4*)(xr + kk * 32);
            v[2 * kk + 1] = *(const float4*)(xr + kk * 32 + 4);
        }
    }

#pragma unroll
    for (int it = 0; it < 4; it++) {
        int row0 = (t0 + it) * 16;
        if (row0 >= n) break;

        // convert current tile to bf16 A-frags (consumes v)
        bf16x8 a[4];
#pragma unroll
        for (int kk = 0; kk < 4; kk++) {
            float4 v0 = v[2 * kk], v1 = v[2 * kk + 1];
            a[kk][0] = (short)f2bf(v0.x); a[kk][1] = (short)f2bf(v0.y);
            a[kk][2] = (short)f2bf(v0.z); a[kk][3] = (short)f2bf(v0.w);
            a[kk][4] = (short)f2bf(v1.x); a[kk][5] = (short)f2bf(v1.y);
            a[kk][6] = (short)f2bf(v1.z); a[kk][7] = (short)f2bf(v1.w);
        }

        // prefetch next tile's x while MFMAs run (row-clamped)
        if (it < 3) {
            int arow = row0 + 16 + m; if (arow >= n) arow = n - 1;
            const float* xr = x + (size_t)arow * 128 + quad * 8;
#pragma unroll
            for (int kk = 0; kk < 4; kk++) {
                v[2 * kk]     = *(const float4*)(xr + kk * 32);
                v[2 * kk + 1] = *(const float4*)(xr + kk * 32 + 4);
            }
        }

        f32x4 acc[4];
#pragma unroll
        for (int t = 0; t < 4; t++) acc[t] = (f32x4){0.f, 0.f, 0.f, 0.f};
#pragma unroll
        for (int kk = 0; kk < 4; kk++) {
            bf16x8 bq[4];
#pragma unroll
            for (int t = 0; t < 4; t++)
                bq[t] = *(const bf16x8*)(Blds + ((kk * 4 + quad) * 64 + t * 16 + m) * 8);
#pragma unroll
            for (int t = 0; t < 4; t++)
                acc[t] = __builtin_amdgcn_mfma_f32_16x16x32_bf16(a[kk], bq[t], acc[t], 0, 0, 0);
        }

#pragma unroll
        for (int r = 0; r < 4; r++) {
            int orow = row0 + quad * 4 + r;
            if (orow < n) {
                ushort4 o4;
                o4.x = f2bf(acc[0][r]); o4.y = f2bf(acc[1][r]);
                o4.z = f2bf(acc[2][r]); o4.w = f2bf(acc[3][r]);
                *(ushort4*)(up + (size_t)orow * 64 + m * 4) = o4;
            }
        }
    }
}

// ---- agg64: 8 nodes/wave (degree-sorted via perm), batched-8 edge loop -----
// MODE 0: outb = A*in + addv, d2 = A*deg fused
// MODE 1: outb = A*in + addv
// MODE 2: outf = A*in + addv + B0 + deg*B1 + d2*B2   (final f32 output)
template <int MODE>
__global__ __launch_bounds__(256) void agg64_kernel(
    const unsigned short* __restrict__ in, const unsigned short* __restrict__ addv,
    const int* __restrict__ csr, const int* __restrict__ start, const int* __restrict__ deg,
    const int* __restrict__ perm,
    unsigned short* __restrict__ outb, float* __restrict__ outf,
    const float* __restrict__ Bv, int* __restrict__ d2w, const int* __restrict__ d2r, int n) {
    int tid = threadIdx.x;
    int fl  = tid & 7;                       // lane within 8-lane group
    int idx = blockIdx.x * 32 + (tid >> 3);  // perm slot (degree-sorted)
    if (idx >= n) return;
    int node = perm[idx];

    // hoist bias columns (node-independent) for MODE 2
    float b0[8], b1[8], b2[8];
    if (MODE == 2) {
#pragma unroll
        for (int j = 0; j < 8; j++) {
            int o = fl * 8 + j;
            b0[j] = Bv[o]; b1[j] = Bv[64 + o]; b2[j] = Bv[128 + o];
        }
    }

    int s0 = start[node];
    int d  = deg[node];

    float acc[8];
#pragma unroll
    for (int j = 0; j < 8; j++) acc[j] = 0.f;
    int dsum = 0;

    // main: batches of 8 edges — phase 1 loads 8 csr entries (independent),
    // phase 2 issues 8 gathers (overlap via vmcnt FIFO) + accumulate.
    int d8 = d & ~7;
    for (int e0 = 0; e0 < d8; e0 += 8) {
        int sv[8];
#pragma unroll
        for (int k = 0; k < 8; k++) sv[k] = csr[s0 + e0 + k];
#pragma unroll
        for (int k = 0; k < 8; k++) {
            bf16x8 v = *(const bf16x8*)(in + (size_t)sv[k] * 64 + fl * 8);
#pragma unroll
            for (int j = 0; j < 8; j++) acc[j] += bf2f((unsigned short)v[j]);
            if (MODE == 0 && fl == 0) dsum += deg[sv[k]];
        }
    }
    // tail
    for (int i = d8; i < d; i++) {
        int s = csr[s0 + i];
        bf16x8 v = *(const bf16x8*)(in + (size_t)s * 64 + fl * 8);
#pragma unroll
        for (int j = 0; j < 8; j++) acc[j] += bf2f((unsigned short)v[j]);
        if (MODE == 0 && fl == 0) dsum += deg[s];
    }
    if (MODE == 0 && fl == 0) d2w[node] = dsum;

    bf16x8 av = *(const bf16x8*)(addv + (size_t)node * 64 + fl * 8);
    if (MODE < 2) {
        bf16x8 o;
#pragma unroll
        for (int j = 0; j < 8; j++) o[j] = (short)f2bf(acc[j] + bf2f((unsigned short)av[j]));
        *(bf16x8*)(outb + (size_t)node * 64 + fl * 8) = o;
    } else {
        float dg = (float)d;
        float dd = (float)d2r[node];
        float ov[8];
#pragma unroll
        for (int j = 0; j < 8; j++)
            ov[j] = acc[j] + bf2f((unsigned short)av[j]) + b0[j] + dg * b1[j] + dd * b2[j];
        float* op = outf + (size_t)node * 64 + fl * 8;
        *(float4*)(op)     = make_float4(ov[0], ov[1], ov[2], ov[3]);
        *(float4*)(op + 4) = make_float4(ov[4], ov[5], ov[6], ov[7]);
    }
}

// ---------------------------------------------------------------------------
extern "C" void kernel_launch(void* const* d_in, const int* in_sizes, int n_in,
                              void* d_out, int out_size, void* d_ws, size_t ws_size,
                              hipStream_t stream) {
    const float* x      = (const float*)d_in[0];
    const int*   ei     = (const int*)d_in[1];
    const float* W_rel  = (const float*)d_in[2];
    const float* b_rel  = (const float*)d_in[3];
    const float* W_root = (const float*)d_in[4];
    const float* fc_w   = (const float*)d_in[5];
    const float* fc_b   = (const float*)d_in[6];

    const int n = in_sizes[0] / 128;      // 100000
    const int e = in_sizes[1] / 2;        // 1600000
    const int* src = ei;
    const int* dst = ei + e;

    const int NB  = (n + 255) >> 8;       // 391 buckets of 256 nodes
    const int NA  = (e + 2047) / 2048;    // 782 partition blocks
    const int NT  = (n + 15) / 16;        // MFMA row-tiles = 6250
    const int NGB = (NT + 15) / 16;       // row-blocks (16 tiles each) = 391
    const int NGBp = (NGB + 7) & ~7;      // pad to multiple of 8 for swizzle

    char* p = (char*)d_ws;
    auto take = [&](size_t bytes) -> void* {
        void* r = (void*)p;
        p += (bytes + 255) & ~(size_t)255;
        return r;
    };
    unsigned short* U  = (unsigned short*)take((size_t)n * 256 * 2);  // u0..u3
    unsigned short* w1 = (unsigned short*)take((size_t)n * 64 * 2);
    unsigned short* w2 = (unsigned short*)take((size_t)n * 64 * 2);
    int* deg    = (int*)take((size_t)n * 4);
    int* start  = (int*)take((size_t)n * 4);
    int* d2     = (int*)take((size_t)n * 4);
    int* perm   = (int*)take((size_t)n * 4);
    int* csr    = (int*)take((size_t)e * 4);
    unsigned int* bucketed = (unsigned int*)take((size_t)NB * CAPB * 4);
    int* gcur   = (int*)take((size_t)NB * 4);
    float* K0_2 = (float*)take(128 * 64 * 4);
    float* K1_2 = (float*)take(128 * 64 * 4);
    float* K0_1 = (float*)take(128 * 64 * 4);
    float* K1_1 = (float*)take(128 * 64 * 4);
    float* K2_1 = (float*)take(128 * 64 * 4);
    unsigned short* Nw = (unsigned short*)take(64 * 512 * 2);
    float* Bv   = (float*)take(192 * 4);

    size_t n64 = (size_t)n * 64;
    unsigned short* u0 = U;
    unsigned short* u1 = U + n64;
    unsigned short* u2 = U + 2 * n64;
    unsigned short* u3 = U + 3 * n64;

    hipMemsetAsync(gcur, 0, (size_t)NB * 4, stream);
    prep_kernel<<<64 + NA, 512, 0, stream>>>(
        W_rel + 2 * 16384, W_root + 2 * 16384, fc_w, K0_2, K1_2,
        src, dst, gcur, bucketed, e, NA, NB);
    partB_kernel<<<NB, 256, 0, stream>>>(bucketed, gcur, deg, start, csr, perm, n);
    stage2_kernel<<<96, 256, 0, stream>>>(
        W_rel + 16384, W_root + 16384, K0_2, K1_2, K0_1, K1_1, K2_1);
    stage3_kernel<<<129, 256, 0, stream>>>(
        W_rel, W_root, K0_1, K1_1, K2_1, K0_2, K1_2, b_rel, fc_w, fc_b, Nw, Bv);

    gemm_u_kernel<<<NGBp * 4, 256, 0, stream>>>(x, Nw, U, n, NGB);

    const int AGB = (n + 31) / 32;        // 32 perm slots per 256-thread block
    // w1 = A u3 + u2 ; w2 = A w1 + u1 ; out = A w2 + u0 + B0 + deg B1 + d2 B2
    agg64_kernel<0><<<AGB, 256, 0, stream>>>(
        u3, u2, csr, start, deg, perm, w1, nullptr, nullptr, d2, nullptr, n);
    agg64_kernel<1><<<AGB, 256, 0, stream>>>(
        w1, u1, csr, start, deg, perm, w2, nullptr, nullptr, nullptr, nullptr, n);
    agg64_kernel<2><<<AGB, 256, 0, stream>>>(
        w2, u0, csr, start, deg, perm, nullptr, (float*)d_out, Bv, nullptr, d2, n);
}

// Round 13
// 307.634 us; speedup vs baseline: 1.0832x; 1.0832x over previous
//
#include <hip/hip_runtime.h>

// ---------------------------------------------------------------------------
// GraphConv x3 + FC on MI355X — R19: R17 + fused scalar pipeline (7 launches).
// Identity: (A x0)K1 + (A^2 x0)K2 + (A^3 x0)K3 = A(u1 + A(u2 + A u3)),
// u_m = x0 K_m (N x 64). 64-dim propagation (128B gather rows).
// R19: R18's degree-sort perm broke write locality (FETCH +17MB, agg 43->49)
// -> reverted. New: stages_kernel (64 blocks, one per output column o)
// computes K-chain columns c02,c12 -> c01,c11,c21 -> Nw + Bv entirely in
// LDS, replacing prep's matmul blocks + stage2 + stage3 + gcur memset.
// Dispatches 10 -> 7 (launch-gap recovery). gemm_u/agg64 = R17 verbatim.
// ---------------------------------------------------------------------------

typedef short bf16x8 __attribute__((ext_vector_type(8)));
typedef float f32x4 __attribute__((ext_vector_type(4)));

#define CAPB 8192   // bucket capacity (mean 4082, sigma ~64 -> 64 sigma slack)

__device__ inline float bf2f(unsigned short u) {
    union { unsigned int i; float f; } v; v.i = ((unsigned int)u) << 16; return v.f;
}
__device__ inline unsigned short f2bf(float f) {
    union { float f; unsigned int i; } v; v.f = f;
    unsigned int r = v.i + 0x7FFFu + ((v.i >> 16) & 1u);   // RNE
    return (unsigned short)(r >> 16);
}

// ---- stages: per-output-column weight chain + bias + gcur zero -------------
// Block o (0..63): c02=Wo2^T fcw_o, c12=Wr2^T fcw_o; c01=Wo1^T c02,
// c11=Wr1^T c02 + Wo1^T c12, c21=Wr1^T c12; Nw cols (4 matids) + Bv[o,64+o,128+o].
__global__ __launch_bounds__(256) void stages_kernel(
    const float* __restrict__ Wr0, const float* __restrict__ Wo0,
    const float* __restrict__ Wr1, const float* __restrict__ Wo1,
    const float* __restrict__ Wr2, const float* __restrict__ Wo2,
    const float* __restrict__ fcw, const float* __restrict__ fcb,
    const float* __restrict__ br, unsigned short* __restrict__ Nw,
    float* __restrict__ Bv, int* __restrict__ gcur, int NB) {
    int o = blockIdx.x;
    int t = threadIdx.x;
    __shared__ float c02[128], c12[128], c01[128], c11[128], c21[128];
    __shared__ float redbuf[3][128];

    if (o == 0) {                       // zero gcur for prep (stream-ordered)
        for (int q = t; q < NB; q += 256) gcur[q] = 0;
    }

    const float* fo = fcw + (size_t)o * 128;
    int i  = t & 127;
    int hi = t >> 7;

    // P1: c02 (hi=0, Wo2), c12 (hi=1, Wr2)
    {
        const float* W = hi ? Wr2 : Wo2;
        float acc = 0.f;
        for (int k = 0; k < 128; k++) acc += W[k * 128 + i] * fo[k];
        (hi ? c12 : c02)[i] = acc;
    }
    __syncthreads();

    // P2: hi=0 -> c01 & c21 ; hi=1 -> c11 (2 dots each side, balanced)
    if (!hi) {
        float a0 = 0.f, a2 = 0.f;
        for (int k = 0; k < 128; k++) {
            float w1o = Wo1[k * 128 + i], w1r = Wr1[k * 128 + i];
            a0 += w1o * c02[k];
            a2 += w1r * c12[k];
        }
        c01[i] = a0; c21[i] = a2;
    } else {
        float a1 = 0.f;
        for (int k = 0; k < 128; k++)
            a1 += Wr1[k * 128 + i] * c02[k] + Wo1[k * 128 + i] * c12[k];
        c11[i] = a1;
    }
    __syncthreads();

    // P3: Nw columns. hi=0 -> matid 0 & 2 ; hi=1 -> matid 1 & 3.
    {
        int p = ((o & 3) << 4) | (o >> 2);
        if (!hi) {
            float a0 = 0.f, a2 = 0.f;
            for (int k = 0; k < 128; k++) {
                float w0 = Wo0[k * 128 + i], wr = Wr0[k * 128 + i];
                a0 += w0 * c01[k];
                a2 += wr * c11[k] + w0 * c21[k];
            }
            Nw[(size_t)p * 512 + 0 * 128 + i] = f2bf(a0);
            Nw[(size_t)p * 512 + 2 * 128 + i] = f2bf(a2);
        } else {
            float a1 = 0.f, a3 = 0.f;
            for (int k = 0; k < 128; k++) {
                float w0 = Wo0[k * 128 + i], wr = Wr0[k * 128 + i];
                a1 += wr * c01[k] + w0 * c11[k];
                a3 += wr * c21[k];
            }
            Nw[(size_t)p * 512 + 1 * 128 + i] = f2bf(a1);
            Nw[(size_t)p * 512 + 3 * 128 + i] = f2bf(a3);
        }
    }

    // P4: bias partials -> wave reductions
    const float* br0 = br;
    const float* br1 = br + 128;
    const float* br2 = br + 256;
    if (!hi) {
        redbuf[0][i] = br2[i] * fo[i] + br1[i] * c02[i] + br0[i] * c01[i];
        redbuf[1][i] = br1[i] * c12[i] + br0[i] * c11[i];
        redbuf[2][i] = br0[i] * c21[i];
    }
    __syncthreads();
    int w = t >> 6, lane = t & 63;
    if (w < 3) {
        float v = redbuf[w][lane] + redbuf[w][lane + 64];
        for (int off = 32; off; off >>= 1) v += __shfl_down(v, off);
        if (lane == 0) Bv[w * 64 + o] = v + (w == 0 ? fcb[o] : 0.f);
    }
}

// ---- prep: edge partition into 256-node buckets ----------------------------
__global__ __launch_bounds__(512) void prep_kernel(
    const int* __restrict__ src, const int* __restrict__ dst,
    int* __restrict__ gcur, unsigned int* __restrict__ bucketed, int e, int NA, int NB) {
    int b = blockIdx.x, t = threadIdx.x;
    if (b < NA) {
        __shared__ int sHist[512], sScan[512], sExcl[512], sGbase[512];
        __shared__ unsigned int lbuf[2048];
        __shared__ unsigned short lbkt[2048];
        int e0 = b * 2048;
        int cnt = e - e0; if (cnt > 2048) cnt = 2048;
        sHist[t] = 0;
        __syncthreads();
        unsigned int pk[4]; int bk[4];
#pragma unroll
        for (int k = 0; k < 4; k++) {
            int j = t + k * 512;
            if (j < cnt) {
                int d = dst[e0 + j], s = src[e0 + j];
                bk[k] = d >> 8;
                pk[k] = ((unsigned int)s << 8) | (unsigned int)(d & 255);
                atomicAdd(&sHist[bk[k]], 1);
            } else bk[k] = -1;
        }
        __syncthreads();
        int h = sHist[t];
        if (t < NB && h > 0) sGbase[t] = atomicAdd(&gcur[t], h);
        else sGbase[t] = 0;
        int xv = h; sScan[t] = xv; __syncthreads();
        for (int o = 1; o < 512; o <<= 1) {
            int y = (t >= o) ? sScan[t - o] : 0;
            __syncthreads();
            xv += y; sScan[t] = xv;
            __syncthreads();
        }
        sExcl[t] = xv - h;      // block-local exclusive offsets per bucket
        sHist[t] = 0;           // becomes local cursor
        __syncthreads();
#pragma unroll
        for (int k = 0; k < 4; k++) {
            if (bk[k] >= 0) {
                int r = atomicAdd(&sHist[bk[k]], 1);
                int pos = sExcl[bk[k]] + r;
                lbuf[pos] = pk[k];
                lbkt[pos] = (unsigned short)bk[k];
            }
        }
        __syncthreads();
        for (int j = t; j < cnt; j += 512) {
            int b2 = lbkt[j];
            int idx = sGbase[b2] + (j - sExcl[b2]);
            if (idx < CAPB) bucketed[(size_t)b2 * CAPB + idx] = lbuf[j];
        }
    }
}

// ---- pass B: per-bucket deg/start/csr --------------------------------------
__global__ __launch_bounds__(256) void partB_kernel(
    const unsigned int* __restrict__ bucketed, const int* __restrict__ gcur,
    int* __restrict__ deg, int* __restrict__ start, int* __restrict__ csr, int n) {
    int b = blockIdx.x, t = threadIdx.x;
    __shared__ int ldeg[256], lscan[256], red[256];
    __shared__ int csr_base_s;
    int cnt = gcur[b]; if (cnt > CAPB) cnt = CAPB;
    // csr base = sum of counts of buckets < b
    int part = 0;
    for (int q = t; q < b; q += 256) { int c = gcur[q]; part += (c > CAPB ? CAPB : c); }
    red[t] = part; __syncthreads();
    for (int o = 128; o > 0; o >>= 1) { if (t < o) red[t] += red[t + o]; __syncthreads(); }
    if (t == 0) csr_base_s = red[0];
    ldeg[t] = 0;
    __syncthreads();
    const unsigned int* bd = bucketed + (size_t)b * CAPB;
    for (int j = t; j < cnt; j += 256) atomicAdd(&ldeg[bd[j] & 255], 1);
    __syncthreads();
    int h = ldeg[t];
    int xv = h; lscan[t] = xv; __syncthreads();
    for (int o = 1; o < 256; o <<= 1) {
        int y = (t >= o) ? lscan[t - o] : 0;
        __syncthreads();
        xv += y; lscan[t] = xv;
        __syncthreads();
    }
    int excl = xv - h;
    int csr_base = csr_base_s;
    int node = b * 256 + t;
    if (node < n) { deg[node] = h; start[node] = csr_base + excl; }
    __syncthreads();
    lscan[t] = excl;    // per-local-node exclusive offset
    ldeg[t] = 0;        // cursor
    __syncthreads();
    for (int j = t; j < cnt; j += 256) {
        unsigned int pkd = bd[j];
        int d = pkd & 255;
        int r = atomicAdd(&ldeg[d], 1);
        csr[csr_base + lscan[d] + r] = (int)(pkd >> 8);
    }
}

// ---- gemm_u: U[m][n][64] = bf16(x0 @ K_m), m=0..3, MFMA ---------------------
// Sibling swizzle: xcd=bid&7, matid=(bid>>3)&3, blk=(bid>>5)*8+xcd so the 4
// blocks sharing x rows land on the same XCD. B-panel staged in LDS once.
// 4 waves x 4 tiles per block with 1-tile x prefetch (regs: a16+v32+acc16+bq16).
__global__ __launch_bounds__(256, 4) void gemm_u_kernel(
    const float* __restrict__ x, const unsigned short* __restrict__ Nw,
    unsigned short* __restrict__ U, int n, int NGB) {
    __shared__ unsigned short Blds[8192];   // 16 KB
    int bid   = blockIdx.x;
    int matid = (bid >> 3) & 3;
    int blk   = (bid >> 5) * 8 + (bid & 7);
    if (blk >= NGB) return;                 // uniform per block (before syncthreads)
    int tid   = threadIdx.x;

    // stage B[matid]: 1024 x 16B groups, contiguous LDS writes
    {
        const uint4* nw4 = (const uint4*)Nw;   // Nw: 64 slots x 512 elems = 64 x 64 uint4
        uint4* lds4 = (uint4*)Blds;
        for (int g = tid; g < 1024; g += 256) {
            int slot = g & 63;
            int kq   = g >> 6;                 // kk*4+quad
            lds4[g] = nw4[(size_t)slot * 64 + matid * 16 + kq];
        }
    }
    __syncthreads();

    int wave = tid >> 6;
    int lane = tid & 63;
    int m    = lane & 15;
    int quad = lane >> 4;
    size_t n64 = (size_t)n * 64;
    unsigned short* up = U + (size_t)matid * n64;

    const int t0 = blk * 16 + wave * 4;

    // prologue: load tile t0 (row-clamped)
    float4 v[8];
    {
        int arow = t0 * 16 + m; if (arow >= n) arow = n - 1;
        const float* xr = x + (size_t)arow * 128 + quad * 8;
#pragma unroll
        for (int kk = 0; kk < 4; kk++) {
            v[2 * kk]     = *(const float4*)(xr + kk * 32);
            v[2 * kk + 1] = *(const float4*)(xr + kk * 32 + 4);
        }
    }

#pragma unroll
    for (int it = 0; it < 4; it++) {
        int row0 = (t0 + it) * 16;
        if (row0 >= n) break;

        // convert current tile to bf16 A-frags (consumes v)
        bf16x8 a[4];
#pragma unroll
        for (int kk = 0; kk < 4; kk++) {
            float4 v0 = v[2 * kk], v1 = v[2 * kk + 1];
            a[kk][0] = (short)f2bf(v0.x); a[kk][1] = (short)f2bf(v0.y);
            a[kk][2] = (short)f2bf(v0.z); a[kk][3] = (short)f2bf(v0.w);
            a[kk][4] = (short)f2bf(v1.x); a[kk][5] = (short)f2bf(v1.y);
            a[kk][6] = (short)f2bf(v1.z); a[kk][7] = (short)f2bf(v1.w);
        }

        // prefetch next tile's x while MFMAs run (row-clamped)
        if (it < 3) {
            int arow = row0 + 16 + m; if (arow >= n) arow = n - 1;
            const float* xr = x + (size_t)arow * 128 + quad * 8;
#pragma unroll
            for (int kk = 0; kk < 4; kk++) {
                v[2 * kk]     = *(const float4*)(xr + kk * 32);
                v[2 * kk + 1] = *(const float4*)(xr + kk * 32 + 4);
            }
        }

        f32x4 acc[4];
#pragma unroll
        for (int t = 0; t < 4; t++) acc[t] = (f32x4){0.f, 0.f, 0.f, 0.f};
#pragma unroll
        for (int kk = 0; kk < 4; kk++) {
            bf16x8 bq[4];
#pragma unroll
            for (int t = 0; t < 4; t++)
                bq[t] = *(const bf16x8*)(Blds + ((kk * 4 + quad) * 64 + t * 16 + m) * 8);
#pragma unroll
            for (int t = 0; t < 4; t++)
                acc[t] = __builtin_amdgcn_mfma_f32_16x16x32_bf16(a[kk], bq[t], acc[t], 0, 0, 0);
        }

#pragma unroll
        for (int r = 0; r < 4; r++) {
            int orow = row0 + quad * 4 + r;
            if (orow < n) {
                ushort4 o4;
                o4.x = f2bf(acc[0][r]); o4.y = f2bf(acc[1][r]);
                o4.z = f2bf(acc[2][r]); o4.w = f2bf(acc[3][r]);
                *(ushort4*)(up + (size_t)orow * 64 + m * 4) = o4;
            }
        }
    }
}

// ---- agg64: 8 nodes/wave, 8-lane group per node, two-phase batched-8 loop --
// MODE 0: outb = A*in + addv, d2 = A*deg fused
// MODE 1: outb = A*in + addv
// MODE 2: outf = A*in + addv + B0 + deg*B1 + d2*B2   (final f32 output)
template <int MODE>
__global__ __launch_bounds__(256) void agg64_kernel(
    const unsigned short* __restrict__ in, const unsigned short* __restrict__ addv,
    const int* __restrict__ csr, const int* __restrict__ start, const int* __restrict__ deg,
    unsigned short* __restrict__ outb, float* __restrict__ outf,
    const float* __restrict__ Bv, int* __restrict__ d2w, const int* __restrict__ d2r, int n) {
    int tid = threadIdx.x;
    int fl  = tid & 7;                       // lane within 8-lane group
    int node = blockIdx.x * 32 + (tid >> 3); // one node per group
    if (node >= n) return;

    // hoist bias columns (node-independent) for MODE 2
    float b0[8], b1[8], b2[8];
    if (MODE == 2) {
#pragma unroll
        for (int j = 0; j < 8; j++) {
            int o = fl * 8 + j;
            b0[j] = Bv[o]; b1[j] = Bv[64 + o]; b2[j] = Bv[128 + o];
        }
    }

    int s0 = start[node];
    int d  = deg[node];

    float acc[8];
#pragma unroll
    for (int j = 0; j < 8; j++) acc[j] = 0.f;
    int dsum = 0;

    // main: batches of 8 edges — phase 1 loads 8 csr entries (independent),
    // phase 2 issues 8 gathers (overlap via vmcnt FIFO) + accumulate.
    int d8 = d & ~7;
    for (int e0 = 0; e0 < d8; e0 += 8) {
        int sv[8];
#pragma unroll
        for (int k = 0; k < 8; k++) sv[k] = csr[s0 + e0 + k];
#pragma unroll
        for (int k = 0; k < 8; k++) {
            bf16x8 v = *(const bf16x8*)(in + (size_t)sv[k] * 64 + fl * 8);
#pragma unroll
            for (int j = 0; j < 8; j++) acc[j] += bf2f((unsigned short)v[j]);
            if (MODE == 0 && fl == 0) dsum += deg[sv[k]];
        }
    }
    // tail
    for (int i = d8; i < d; i++) {
        int s = csr[s0 + i];
        bf16x8 v = *(const bf16x8*)(in + (size_t)s * 64 + fl * 8);
#pragma unroll
        for (int j = 0; j < 8; j++) acc[j] += bf2f((unsigned short)v[j]);
        if (MODE == 0 && fl == 0) dsum += deg[s];
    }
    if (MODE == 0 && fl == 0) d2w[node] = dsum;

    bf16x8 av = *(const bf16x8*)(addv + (size_t)node * 64 + fl * 8);
    if (MODE < 2) {
        bf16x8 o;
#pragma unroll
        for (int j = 0; j < 8; j++) o[j] = (short)f2bf(acc[j] + bf2f((unsigned short)av[j]));
        *(bf16x8*)(outb + (size_t)node * 64 + fl * 8) = o;
    } else {
        float dg = (float)d;
        float dd = (float)d2r[node];
        float ov[8];
#pragma unroll
        for (int j = 0; j < 8; j++)
            ov[j] = acc[j] + bf2f((unsigned short)av[j]) + b0[j] + dg * b1[j] + dd * b2[j];
        float* op = outf + (size_t)node * 64 + fl * 8;
        *(float4*)(op)     = make_float4(ov[0], ov[1], ov[2], ov[3]);
        *(float4*)(op + 4) = make_float4(ov[4], ov[5], ov[6], ov[7]);
    }
}

// ---------------------------------------------------------------------------
extern "C" void kernel_launch(void* const* d_in, const int* in_sizes, int n_in,
                              void* d_out, int out_size, void* d_ws, size_t ws_size,
                              hipStream_t stream) {
    const float* x      = (const float*)d_in[0];
    const int*   ei     = (const int*)d_in[1];
    const float* W_rel  = (const float*)d_in[2];
    const float* b_rel  = (const float*)d_in[3];
    const float* W_root = (const float*)d_in[4];
    const float* fc_w   = (const float*)d_in[5];
    const float* fc_b   = (const float*)d_in[6];

    const int n = in_sizes[0] / 128;      // 100000
    const int e = in_sizes[1] / 2;        // 1600000
    const int* src = ei;
    const int* dst = ei + e;

    const int NB  = (n + 255) >> 8;       // 391 buckets of 256 nodes
    const int NA  = (e + 2047) / 2048;    // 782 partition blocks
    const int NT  = (n + 15) / 16;        // MFMA row-tiles = 6250
    const int NGB = (NT + 15) / 16;       // row-blocks (16 tiles each) = 391
    const int NGBp = (NGB + 7) & ~7;      // pad to multiple of 8 for swizzle

    char* p = (char*)d_ws;
    auto take = [&](size_t bytes) -> void* {
        void* r = (void*)p;
        p += (bytes + 255) & ~(size_t)255;
        return r;
    };
    unsigned short* U  = (unsigned short*)take((size_t)n * 256 * 2);  // u0..u3
    unsigned short* w1 = (unsigned short*)take((size_t)n * 64 * 2);
    unsigned short* w2 = (unsigned short*)take((size_t)n * 64 * 2);
    int* deg    = (int*)take((size_t)n * 4);
    int* start  = (int*)take((size_t)n * 4);
    int* d2     = (int*)take((size_t)n * 4);
    int* csr    = (int*)take((size_t)e * 4);
    unsigned int* bucketed = (unsigned int*)take((size_t)NB * CAPB * 4);
    int* gcur   = (int*)take((size_t)NB * 4);
    unsigned short* Nw = (unsigned short*)take(64 * 512 * 2);
    float* Bv   = (float*)take(192 * 4);

    size_t n64 = (size_t)n * 64;
    unsigned short* u0 = U;
    unsigned short* u1 = U + n64;
    unsigned short* u2 = U + 2 * n64;
    unsigned short* u3 = U + 3 * n64;

    // stages first: computes Nw/Bv AND zeros gcur (stream-ordered before prep)
    stages_kernel<<<64, 256, 0, stream>>>(
        W_rel, W_root, W_rel + 16384, W_root + 16384,
        W_rel + 2 * 16384, W_root + 2 * 16384,
        fc_w, fc_b, b_rel, Nw, Bv, gcur, NB);
    prep_kernel<<<NA, 512, 0, stream>>>(src, dst, gcur, bucketed, e, NA, NB);
    partB_kernel<<<NB, 256, 0, stream>>>(bucketed, gcur, deg, start, csr, n);

    gemm_u_kernel<<<NGBp * 4, 256, 0, stream>>>(x, Nw, U, n, NGB);

    const int AGB = (n + 31) / 32;        // 32 nodes per 256-thread block
    // w1 = A u3 + u2 ; w2 = A w1 + u1 ; out = A w2 + u0 + B0 + deg B1 + d2 B2
    agg64_kernel<0><<<AGB, 256, 0, stream>>>(
        u3, u2, csr, start, deg, w1, nullptr, nullptr, d2, nullptr, n);
    agg64_kernel<1><<<AGB, 256, 0, stream>>>(
        w1, u1, csr, start, deg, w2, nullptr, nullptr, nullptr, nullptr, n);
    agg64_kernel<2><<<AGB, 256, 0, stream>>>(
        w2, u0, csr, start, deg, nullptr, (float*)d_out, Bv, nullptr, d2, n);
}

// Round 14
// 297.477 us; speedup vs baseline: 1.1202x; 1.0341x over previous
//
#include <hip/hip_runtime.h>

// ---------------------------------------------------------------------------
// GraphConv x3 + FC on MI355X — R20: prep ∥ gemm_u fused (6 launches).
// Identity: (A x0)K1 + (A^2 x0)K2 + (A^3 x0)K3 = A(u1 + A(u2 + A u3)),
// u_m = x0 K_m (N x 64). 64-dim propagation (128B gather rows).
// R20: accounting showed prep+partB ~110us hiding under the top-5 cutoff.
// gemm_u is independent of the CSR build, so prep and gemm_u now run as two
// block-ranges of ONE kernel (prep blocks first -> critical path to partB
// starts immediately; gemm blocks fill the rest). 512-thread blocks; gemm
// role stages B with all 512, syncs once, waves 4-7 exit. LDS via union.
// stages/partB/agg64 byte-identical to R19 (measured).
// ---------------------------------------------------------------------------

typedef short bf16x8 __attribute__((ext_vector_type(8)));
typedef float f32x4 __attribute__((ext_vector_type(4)));

#define CAPB 8192   // bucket capacity (mean 4082, sigma ~64 -> 64 sigma slack)

__device__ inline float bf2f(unsigned short u) {
    union { unsigned int i; float f; } v; v.i = ((unsigned int)u) << 16; return v.f;
}
__device__ inline unsigned short f2bf(float f) {
    union { float f; unsigned int i; } v; v.f = f;
    unsigned int r = v.i + 0x7FFFu + ((v.i >> 16) & 1u);   // RNE
    return (unsigned short)(r >> 16);
}

// ---- stages: per-output-column weight chain + bias + gcur zero -------------
__global__ __launch_bounds__(256) void stages_kernel(
    const float* __restrict__ Wr0, const float* __restrict__ Wo0,
    const float* __restrict__ Wr1, const float* __restrict__ Wo1,
    const float* __restrict__ Wr2, const float* __restrict__ Wo2,
    const float* __restrict__ fcw, const float* __restrict__ fcb,
    const float* __restrict__ br, unsigned short* __restrict__ Nw,
    float* __restrict__ Bv, int* __restrict__ gcur, int NB) {
    int o = blockIdx.x;
    int t = threadIdx.x;
    __shared__ float c02[128], c12[128], c01[128], c11[128], c21[128];
    __shared__ float redbuf[3][128];

    if (o == 0) {                       // zero gcur for prep (stream-ordered)
        for (int q = t; q < NB; q += 256) gcur[q] = 0;
    }

    const float* fo = fcw + (size_t)o * 128;
    int i  = t & 127;
    int hi = t >> 7;

    // P1: c02 (hi=0, Wo2), c12 (hi=1, Wr2)
    {
        const float* W = hi ? Wr2 : Wo2;
        float acc = 0.f;
        for (int k = 0; k < 128; k++) acc += W[k * 128 + i] * fo[k];
        (hi ? c12 : c02)[i] = acc;
    }
    __syncthreads();

    // P2: hi=0 -> c01 & c21 ; hi=1 -> c11
    if (!hi) {
        float a0 = 0.f, a2 = 0.f;
        for (int k = 0; k < 128; k++) {
            float w1o = Wo1[k * 128 + i], w1r = Wr1[k * 128 + i];
            a0 += w1o * c02[k];
            a2 += w1r * c12[k];
        }
        c01[i] = a0; c21[i] = a2;
    } else {
        float a1 = 0.f;
        for (int k = 0; k < 128; k++)
            a1 += Wr1[k * 128 + i] * c02[k] + Wo1[k * 128 + i] * c12[k];
        c11[i] = a1;
    }
    __syncthreads();

    // P3: Nw columns. hi=0 -> matid 0 & 2 ; hi=1 -> matid 1 & 3.
    {
        int p = ((o & 3) << 4) | (o >> 2);
        if (!hi) {
            float a0 = 0.f, a2 = 0.f;
            for (int k = 0; k < 128; k++) {
                float w0 = Wo0[k * 128 + i], wr = Wr0[k * 128 + i];
                a0 += w0 * c01[k];
                a2 += wr * c11[k] + w0 * c21[k];
            }
            Nw[(size_t)p * 512 + 0 * 128 + i] = f2bf(a0);
            Nw[(size_t)p * 512 + 2 * 128 + i] = f2bf(a2);
        } else {
            float a1 = 0.f, a3 = 0.f;
            for (int k = 0; k < 128; k++) {
                float w0 = Wo0[k * 128 + i], wr = Wr0[k * 128 + i];
                a1 += wr * c01[k] + w0 * c11[k];
                a3 += wr * c21[k];
            }
            Nw[(size_t)p * 512 + 1 * 128 + i] = f2bf(a1);
            Nw[(size_t)p * 512 + 3 * 128 + i] = f2bf(a3);
        }
    }

    // P4: bias partials -> wave reductions
    const float* br0 = br;
    const float* br1 = br + 128;
    const float* br2 = br + 256;
    if (!hi) {
        redbuf[0][i] = br2[i] * fo[i] + br1[i] * c02[i] + br0[i] * c01[i];
        redbuf[1][i] = br1[i] * c12[i] + br0[i] * c11[i];
        redbuf[2][i] = br0[i] * c21[i];
    }
    __syncthreads();
    int w = t >> 6, lane = t & 63;
    if (w < 3) {
        float v = redbuf[w][lane] + redbuf[w][lane + 64];
        for (int off = 32; off; off >>= 1) v += __shfl_down(v, off);
        if (lane == 0) Bv[w * 64 + o] = v + (w == 0 ? fcb[o] : 0.f);
    }
}

// ---- fused: prep role (blocks [0,NA)) ∥ gemm_u role (blocks [NA, NA+G)) ----
union FusedSmem {
    struct {
        int sHist[512], sScan[512], sExcl[512], sGbase[512];
        unsigned int lbuf[2048];
        unsigned short lbkt[2048];
    } pr;
    unsigned short Blds[8192];   // 16 KB (gemm B-panel)
};

__global__ __launch_bounds__(512, 4) void fused_kernel(
    const int* __restrict__ src, const int* __restrict__ dst,
    int* __restrict__ gcur, unsigned int* __restrict__ bucketed, int e, int NA, int NB,
    const float* __restrict__ x, const unsigned short* __restrict__ Nw,
    unsigned short* __restrict__ U, int n, int NGB) {
    __shared__ FusedSmem sm;
    int bid = blockIdx.x;
    int t   = threadIdx.x;

    if (bid < NA) {
        // ---------------- prep role (verbatim R19, 512 threads) ------------
        int b = bid;
        int e0 = b * 2048;
        int cnt = e - e0; if (cnt > 2048) cnt = 2048;
        sm.pr.sHist[t] = 0;
        __syncthreads();
        unsigned int pk[4]; int bk[4];
#pragma unroll
        for (int k = 0; k < 4; k++) {
            int j = t + k * 512;
            if (j < cnt) {
                int d = dst[e0 + j], s = src[e0 + j];
                bk[k] = d >> 8;
                pk[k] = ((unsigned int)s << 8) | (unsigned int)(d & 255);
                atomicAdd(&sm.pr.sHist[bk[k]], 1);
            } else bk[k] = -1;
        }
        __syncthreads();
        int h = sm.pr.sHist[t];
        if (t < NB && h > 0) sm.pr.sGbase[t] = atomicAdd(&gcur[t], h);
        else sm.pr.sGbase[t] = 0;
        int xv = h; sm.pr.sScan[t] = xv; __syncthreads();
        for (int o = 1; o < 512; o <<= 1) {
            int y = (t >= o) ? sm.pr.sScan[t - o] : 0;
            __syncthreads();
            xv += y; sm.pr.sScan[t] = xv;
            __syncthreads();
        }
        sm.pr.sExcl[t] = xv - h;    // block-local exclusive offsets per bucket
        sm.pr.sHist[t] = 0;         // becomes local cursor
        __syncthreads();
#pragma unroll
        for (int k = 0; k < 4; k++) {
            if (bk[k] >= 0) {
                int r = atomicAdd(&sm.pr.sHist[bk[k]], 1);
                int pos = sm.pr.sExcl[bk[k]] + r;
                sm.pr.lbuf[pos] = pk[k];
                sm.pr.lbkt[pos] = (unsigned short)bk[k];
            }
        }
        __syncthreads();
        for (int j = t; j < cnt; j += 512) {
            int b2 = sm.pr.lbkt[j];
            int idx = sm.pr.sGbase[b2] + (j - sm.pr.sExcl[b2]);
            if (idx < CAPB) bucketed[(size_t)b2 * CAPB + idx] = sm.pr.lbuf[j];
        }
        return;
    }

    // ---------------- gemm_u role (R16 structure, 256 active threads) ------
    int gbid  = bid - NA;
    int matid = (gbid >> 3) & 3;
    int blk   = (gbid >> 5) * 8 + (gbid & 7);
    if (blk >= NGB) return;                 // uniform per block (before barrier)

    // stage B[matid]: 1024 x 16B groups, all 512 threads
    {
        const uint4* nw4 = (const uint4*)Nw;   // 64 slots x 64 uint4
        uint4* lds4 = (uint4*)sm.Blds;
        for (int g = t; g < 1024; g += 512) {
            int slot = g & 63;
            int kq   = g >> 6;                 // kk*4+quad
            lds4[g] = nw4[(size_t)slot * 64 + matid * 16 + kq];
        }
    }
    __syncthreads();
    if (t >= 256) return;                   // waves 4-7 exit (no later barriers)

    int wave = t >> 6;
    int lane = t & 63;
    int m    = lane & 15;
    int quad = lane >> 4;
    size_t n64 = (size_t)n * 64;
    unsigned short* up = U + (size_t)matid * n64;

    const int t0 = blk * 16 + wave * 4;

    // prologue: load tile t0 (row-clamped)
    float4 v[8];
    {
        int arow = t0 * 16 + m; if (arow >= n) arow = n - 1;
        const float* xr = x + (size_t)arow * 128 + quad * 8;
#pragma unroll
        for (int kk = 0; kk < 4; kk++) {
            v[2 * kk]     = *(const float4*)(xr + kk * 32);
            v[2 * kk + 1] = *(const float4*)(xr + kk * 32 + 4);
        }
    }

#pragma unroll
    for (int it = 0; it < 4; it++) {
        int row0 = (t0 + it) * 16;
        if (row0 >= n) break;

        bf16x8 a[4];
#pragma unroll
        for (int kk = 0; kk < 4; kk++) {
            float4 v0 = v[2 * kk], v1 = v[2 * kk + 1];
            a[kk][0] = (short)f2bf(v0.x); a[kk][1] = (short)f2bf(v0.y);
            a[kk][2] = (short)f2bf(v0.z); a[kk][3] = (short)f2bf(v0.w);
            a[kk][4] = (short)f2bf(v1.x); a[kk][5] = (short)f2bf(v1.y);
            a[kk][6] = (short)f2bf(v1.z); a[kk][7] = (short)f2bf(v1.w);
        }

        if (it < 3) {
            int arow = row0 + 16 + m; if (arow >= n) arow = n - 1;
            const float* xr = x + (size_t)arow * 128 + quad * 8;
#pragma unroll
            for (int kk = 0; kk < 4; kk++) {
                v[2 * kk]     = *(const float4*)(xr + kk * 32);
                v[2 * kk + 1] = *(const float4*)(xr + kk * 32 + 4);
            }
        }

        f32x4 acc[4];
#pragma unroll
        for (int tt = 0; tt < 4; tt++) acc[tt] = (f32x4){0.f, 0.f, 0.f, 0.f};
#pragma unroll
        for (int kk = 0; kk < 4; kk++) {
            bf16x8 bq[4];
#pragma unroll
            for (int tt = 0; tt < 4; tt++)
                bq[tt] = *(const bf16x8*)(sm.Blds + ((kk * 4 + quad) * 64 + tt * 16 + m) * 8);
#pragma unroll
            for (int tt = 0; tt < 4; tt++)
                acc[tt] = __builtin_amdgcn_mfma_f32_16x16x32_bf16(a[kk], bq[tt], acc[tt], 0, 0, 0);
        }

#pragma unroll
        for (int r = 0; r < 4; r++) {
            int orow = row0 + quad * 4 + r;
            if (orow < n) {
                ushort4 o4;
                o4.x = f2bf(acc[0][r]); o4.y = f2bf(acc[1][r]);
                o4.z = f2bf(acc[2][r]); o4.w = f2bf(acc[3][r]);
                *(ushort4*)(up + (size_t)orow * 64 + m * 4) = o4;
            }
        }
    }
}

// ---- pass B: per-bucket deg/start/csr --------------------------------------
__global__ __launch_bounds__(256) void partB_kernel(
    const unsigned int* __restrict__ bucketed, const int* __restrict__ gcur,
    int* __restrict__ deg, int* __restrict__ start, int* __restrict__ csr, int n) {
    int b = blockIdx.x, t = threadIdx.x;
    __shared__ int ldeg[256], lscan[256], red[256];
    __shared__ int csr_base_s;
    int cnt = gcur[b]; if (cnt > CAPB) cnt = CAPB;
    // csr base = sum of counts of buckets < b
    int part = 0;
    for (int q = t; q < b; q += 256) { int c = gcur[q]; part += (c > CAPB ? CAPB : c); }
    red[t] = part; __syncthreads();
    for (int o = 128; o > 0; o >>= 1) { if (t < o) red[t] += red[t + o]; __syncthreads(); }
    if (t == 0) csr_base_s = red[0];
    ldeg[t] = 0;
    __syncthreads();
    const unsigned int* bd = bucketed + (size_t)b * CAPB;
    for (int j = t; j < cnt; j += 256) atomicAdd(&ldeg[bd[j] & 255], 1);
    __syncthreads();
    int h = ldeg[t];
    int xv = h; lscan[t] = xv; __syncthreads();
    for (int o = 1; o < 256; o <<= 1) {
        int y = (t >= o) ? lscan[t - o] : 0;
        __syncthreads();
        xv += y; lscan[t] = xv;
        __syncthreads();
    }
    int excl = xv - h;
    int csr_base = csr_base_s;
    int node = b * 256 + t;
    if (node < n) { deg[node] = h; start[node] = csr_base + excl; }
    __syncthreads();
    lscan[t] = excl;    // per-local-node exclusive offset
    ldeg[t] = 0;        // cursor
    __syncthreads();
    for (int j = t; j < cnt; j += 256) {
        unsigned int pkd = bd[j];
        int d = pkd & 255;
        int r = atomicAdd(&ldeg[d], 1);
        csr[csr_base + lscan[d] + r] = (int)(pkd >> 8);
    }
}

// ---- agg64: 8 nodes/wave, 8-lane group per node, two-phase batched-8 loop --
// MODE 0: outb = A*in + addv, d2 = A*deg fused
// MODE 1: outb = A*in + addv
// MODE 2: outf = A*in + addv + B0 + deg*B1 + d2*B2   (final f32 output)
template <int MODE>
__global__ __launch_bounds__(256) void agg64_kernel(
    const unsigned short* __restrict__ in, const unsigned short* __restrict__ addv,
    const int* __restrict__ csr, const int* __restrict__ start, const int* __restrict__ deg,
    unsigned short* __restrict__ outb, float* __restrict__ outf,
    const float* __restrict__ Bv, int* __restrict__ d2w, const int* __restrict__ d2r, int n) {
    int tid = threadIdx.x;
    int fl  = tid & 7;                       // lane within 8-lane group
    int node = blockIdx.x * 32 + (tid >> 3); // one node per group
    if (node >= n) return;

    // hoist bias columns (node-independent) for MODE 2
    float b0[8], b1[8], b2[8];
    if (MODE == 2) {
#pragma unroll
        for (int j = 0; j < 8; j++) {
            int o = fl * 8 + j;
            b0[j] = Bv[o]; b1[j] = Bv[64 + o]; b2[j] = Bv[128 + o];
        }
    }

    int s0 = start[node];
    int d  = deg[node];

    float acc[8];
#pragma unroll
    for (int j = 0; j < 8; j++) acc[j] = 0.f;
    int dsum = 0;

    // main: batches of 8 edges — phase 1 loads 8 csr entries (independent),
    // phase 2 issues 8 gathers (overlap via vmcnt FIFO) + accumulate.
    int d8 = d & ~7;
    for (int e0 = 0; e0 < d8; e0 += 8) {
        int sv[8];
#pragma unroll
        for (int k = 0; k < 8; k++) sv[k] = csr[s0 + e0 + k];
#pragma unroll
        for (int k = 0; k < 8; k++) {
            bf16x8 v = *(const bf16x8*)(in + (size_t)sv[k] * 64 + fl * 8);
#pragma unroll
            for (int j = 0; j < 8; j++) acc[j] += bf2f((unsigned short)v[j]);
            if (MODE == 0 && fl == 0) dsum += deg[sv[k]];
        }
    }
    // tail
    for (int i = d8; i < d; i++) {
        int s = csr[s0 + i];
        bf16x8 v = *(const bf16x8*)(in + (size_t)s * 64 + fl * 8);
#pragma unroll
        for (int j = 0; j < 8; j++) acc[j] += bf2f((unsigned short)v[j]);
        if (MODE == 0 && fl == 0) dsum += deg[s];
    }
    if (MODE == 0 && fl == 0) d2w[node] = dsum;

    bf16x8 av = *(const bf16x8*)(addv + (size_t)node * 64 + fl * 8);
    if (MODE < 2) {
        bf16x8 o;
#pragma unroll
        for (int j = 0; j < 8; j++) o[j] = (short)f2bf(acc[j] + bf2f((unsigned short)av[j]));
        *(bf16x8*)(outb + (size_t)node * 64 + fl * 8) = o;
    } else {
        float dg = (float)d;
        float dd = (float)d2r[node];
        float ov[8];
#pragma unroll
        for (int j = 0; j < 8; j++)
            ov[j] = acc[j] + bf2f((unsigned short)av[j]) + b0[j] + dg * b1[j] + dd * b2[j];
        float* op = outf + (size_t)node * 64 + fl * 8;
        *(float4*)(op)     = make_float4(ov[0], ov[1], ov[2], ov[3]);
        *(float4*)(op + 4) = make_float4(ov[4], ov[5], ov[6], ov[7]);
    }
}

// ---------------------------------------------------------------------------
extern "C" void kernel_launch(void* const* d_in, const int* in_sizes, int n_in,
                              void* d_out, int out_size, void* d_ws, size_t ws_size,
                              hipStream_t stream) {
    const float* x      = (const float*)d_in[0];
    const int*   ei     = (const int*)d_in[1];
    const float* W_rel  = (const float*)d_in[2];
    const float* b_rel  = (const float*)d_in[3];
    const float* W_root = (const float*)d_in[4];
    const float* fc_w   = (const float*)d_in[5];
    const float* fc_b   = (const float*)d_in[6];

    const int n = in_sizes[0] / 128;      // 100000
    const int e = in_sizes[1] / 2;        // 1600000
    const int* src = ei;
    const int* dst = ei + e;

    const int NB  = (n + 255) >> 8;       // 391 buckets of 256 nodes
    const int NA  = (e + 2047) / 2048;    // 782 partition blocks
    const int NT  = (n + 15) / 16;        // MFMA row-tiles = 6250
    const int NGB = (NT + 15) / 16;       // row-blocks (16 tiles each) = 391
    const int NGBp = (NGB + 7) & ~7;      // pad to multiple of 8 for swizzle

    char* p = (char*)d_ws;
    auto take = [&](size_t bytes) -> void* {
        void* r = (void*)p;
        p += (bytes + 255) & ~(size_t)255;
        return r;
    };
    unsigned short* U  = (unsigned short*)take((size_t)n * 256 * 2);  // u0..u3
    unsigned short* w1 = (unsigned short*)take((size_t)n * 64 * 2);
    unsigned short* w2 = (unsigned short*)take((size_t)n * 64 * 2);
    int* deg    = (int*)take((size_t)n * 4);
    int* start  = (int*)take((size_t)n * 4);
    int* d2     = (int*)take((size_t)n * 4);
    int* csr    = (int*)take((size_t)e * 4);
    unsigned int* bucketed = (unsigned int*)take((size_t)NB * CAPB * 4);
    int* gcur   = (int*)take((size_t)NB * 4);
    unsigned short* Nw = (unsigned short*)take(64 * 512 * 2);
    float* Bv   = (float*)take(192 * 4);

    size_t n64 = (size_t)n * 64;
    unsigned short* u0 = U;
    unsigned short* u1 = U + n64;
    unsigned short* u2 = U + 2 * n64;
    unsigned short* u3 = U + 3 * n64;

    // stages: computes Nw/Bv AND zeros gcur (stream-ordered before fused)
    stages_kernel<<<64, 256, 0, stream>>>(
        W_rel, W_root, W_rel + 16384, W_root + 16384,
        W_rel + 2 * 16384, W_root + 2 * 16384,
        fc_w, fc_b, b_rel, Nw, Bv, gcur, NB);

    // fused: prep (blocks [0,NA)) ∥ gemm_u (blocks [NA, NA+NGBp*4))
    fused_kernel<<<NA + NGBp * 4, 512, 0, stream>>>(
        src, dst, gcur, bucketed, e, NA, NB, x, Nw, U, n, NGB);

    partB_kernel<<<NB, 256, 0, stream>>>(bucketed, gcur, deg, start, csr, n);

    const int AGB = (n + 31) / 32;        // 32 nodes per 256-thread block
    // w1 = A u3 + u2 ; w2 = A w1 + u1 ; out = A w2 + u0 + B0 + deg B1 + d2 B2
    agg64_kernel<0><<<AGB, 256, 0, stream>>>(
        u3, u2, csr, start, deg, w1, nullptr, nullptr, d2, nullptr, n);
    agg64_kernel<1><<<AGB, 256, 0, stream>>>(
        w1, u1, csr, start, deg, w2, nullptr, nullptr, nullptr, nullptr, n);
    agg64_kernel<2><<<AGB, 256, 0, stream>>>(
        w2, u0, csr, start, deg, nullptr, (float*)d_out, Bv, nullptr, d2, n);
}